// Round 2
// baseline (1578.649 us; speedup 1.0000x reference)
//
#include <hip/hip_runtime.h>
#include <hip/hip_bf16.h>
#include <math.h>

#define T_DIM 4096
#define H_DIM 1024
#define NHEAD 4

#define TT   256   // timesteps per block (== blockDim)
#define CH   32    // H-chunk per LDS stage
#define XSTR 36    // padded LDS row stride in floats (36/4=9 odd -> conflict-free b128)

// ---------------------------------------------------------------------------
// Kernel 1: h[b,t,n] = dot(x[b,t,:], W[n,:]) + bias[n]
// One thread owns one timestep; x staged via LDS (coalesced global, padded
// LDS rows); W broadcast from LDS; no cross-lane reduction at all.
// grid = B*T/TT blocks of 256.
// ---------------------------------------------------------------------------
__global__ __launch_bounds__(256) void ema_gemv(const float* __restrict__ x,
                                                const float* __restrict__ W,
                                                const float* __restrict__ bias,
                                                float* __restrict__ h) {
    __shared__ float xt[TT * XSTR];        // 36 KB
    __shared__ float wl[NHEAD * H_DIM];    // 16 KB

    const int tid = threadIdx.x;
    const size_t g0 = (size_t)blockIdx.x * TT;   // first global row (b*T + t)

    // stage W (4096 floats) into LDS, coalesced
#pragma unroll
    for (int p = 0; p < 4; ++p)
        ((float4*)wl)[p * 256 + tid] = ((const float4*)W)[p * 256 + tid];

    // load-phase assignment: 8 threads per row, 128B contiguous per row-slice
    const int lr = tid >> 3;        // 0..31 (row within pass)
    const int lc = (tid & 7) * 4;   // float offset within chunk

    float4 pf[8];                   // prefetch regs for one chunk
    const float* xbase = x + g0 * H_DIM;

    // prefetch chunk 0
#pragma unroll
    for (int p = 0; p < 8; ++p) {
        const int row = p * 32 + lr;
        pf[p] = *(const float4*)(xbase + (size_t)row * H_DIM + lc);
    }

    float acc[NHEAD] = {0.f, 0.f, 0.f, 0.f};

    for (int c = 0; c < H_DIM / CH; ++c) {
        // write staged regs -> LDS (padded rows)
#pragma unroll
        for (int p = 0; p < 8; ++p) {
            const int row = p * 32 + lr;
            *(float4*)(xt + row * XSTR + lc) = pf[p];
        }
        __syncthreads();

        // issue prefetch of next chunk (consumed next iteration)
        if (c + 1 < H_DIM / CH) {
            const float* xn = xbase + (c + 1) * CH;
#pragma unroll
            for (int p = 0; p < 8; ++p) {
                const int row = p * 32 + lr;
                pf[p] = *(const float4*)(xn + (size_t)row * H_DIM + lc);
            }
        }

        // compute: my row = tid, 32 floats vs all 4 heads
        const float* xr = xt + tid * XSTR;
        const float* wc = wl + c * CH;
#pragma unroll
        for (int k = 0; k < CH; k += 4) {
            const float4 xv = *(const float4*)(xr + k);
#pragma unroll
            for (int n = 0; n < NHEAD; ++n) {
                const float4 wv = *(const float4*)(wc + n * H_DIM + k);
                acc[n] += xv.x * wv.x + xv.y * wv.y + xv.z * wv.z + xv.w * wv.w;
            }
        }
        __syncthreads();
    }

    float4 o;
    o.x = acc[0] + bias[0];
    o.y = acc[1] + bias[1];
    o.z = acc[2] + bias[2];
    o.w = acc[3] + bias[3];
    *(float4*)(h + (g0 + tid) * NHEAD) = o;   // coalesced: consecutive tids -> consecutive 16B
}

// ---------------------------------------------------------------------------
// Kernel 2: per-batch parallel EMA scan + running max + head projection.
// grid = B, block = 256. Thread i owns segment [16i, 16i+16).
// Affine-map composition + Hillis-Steele over 256 segments, then replay
// with carry-in tracking max (max includes the 0 init, matching reference).
// ---------------------------------------------------------------------------
__global__ __launch_bounds__(256) void ema_scan(const float* __restrict__ h,
                                                const float* __restrict__ decay,
                                                const float* __restrict__ head_w,
                                                float* __restrict__ out) {
    const int b    = blockIdx.x;
    const int i    = threadIdx.x;   // 0..255
    const int lane = i & 63;
    const int wave = i >> 6;

    float dd[NHEAD], od[NHEAD];
#pragma unroll
    for (int n = 0; n < NHEAD; ++n) {
        dd[n] = 1.0f / (1.0f + expf(-decay[n]));
        od[n] = 1.0f - dd[n];
    }

    const float4* hrow = (const float4*)(h + (size_t)b * T_DIM * NHEAD);

    // local segment EMA from zero init
    float e[NHEAD] = {0.f, 0.f, 0.f, 0.f};
#pragma unroll
    for (int j = 0; j < 16; ++j) {
        float4 v = hrow[i * 16 + j];
        e[0] = dd[0] * e[0] + od[0] * v.x;
        e[1] = dd[1] * e[1] + od[1] * v.y;
        e[2] = dd[2] * e[2] + od[2] * v.z;
        e[3] = dd[3] * e[3] + od[3] * v.w;
    }
    float a[NHEAD];
#pragma unroll
    for (int n = 0; n < NHEAD; ++n) {
        float d2 = dd[n] * dd[n];
        float d4 = d2 * d2;
        float d8 = d4 * d4;
        a[n] = d8 * d8;   // d^16
    }
    float bb[NHEAD] = {e[0], e[1], e[2], e[3]};

    __shared__ float sA[NHEAD][256];
    __shared__ float sB[NHEAD][256];
#pragma unroll
    for (int n = 0; n < NHEAD; ++n) { sA[n][i] = a[n]; sB[n][i] = bb[n]; }
    __syncthreads();

    for (int off = 1; off < 256; off <<= 1) {
        float pa[NHEAD], pb[NHEAD];
        const bool has = (i >= off);
        if (has) {
#pragma unroll
            for (int n = 0; n < NHEAD; ++n) {
                pa[n] = sA[n][i - off];
                pb[n] = sB[n][i - off];
            }
        }
        __syncthreads();
        if (has) {
#pragma unroll
            for (int n = 0; n < NHEAD; ++n) {
                bb[n] = a[n] * pb[n] + bb[n];  // B_new = A_cur*B_prev + B_cur
                a[n]  = a[n] * pa[n];          // A_new = A_cur*A_prev
            }
        }
#pragma unroll
        for (int n = 0; n < NHEAD; ++n) { sA[n][i] = a[n]; sB[n][i] = bb[n]; }
        __syncthreads();
    }

    // carry-in for my segment = inclusive B of segment i-1 (0 for i==0)
    float e2[NHEAD], m[NHEAD];
#pragma unroll
    for (int n = 0; n < NHEAD; ++n) {
        e2[n] = (i > 0) ? sB[n][i - 1] : 0.0f;
        m[n]  = 0.0f;   // reference's emax starts at 0
    }
#pragma unroll
    for (int j = 0; j < 16; ++j) {
        float4 v = hrow[i * 16 + j];
        e2[0] = dd[0] * e2[0] + od[0] * v.x; m[0] = fmaxf(m[0], e2[0]);
        e2[1] = dd[1] * e2[1] + od[1] * v.y; m[1] = fmaxf(m[1], e2[1]);
        e2[2] = dd[2] * e2[2] + od[2] * v.z; m[2] = fmaxf(m[2], e2[2]);
        e2[3] = dd[3] * e2[3] + od[3] * v.w; m[3] = fmaxf(m[3], e2[3]);
    }

    // 64-lane max butterfly, then cross-wave via LDS
#pragma unroll
    for (int off = 32; off >= 1; off >>= 1)
#pragma unroll
        for (int n = 0; n < NHEAD; ++n)
            m[n] = fmaxf(m[n], __shfl_xor(m[n], off, 64));

    __shared__ float sM[NHEAD][4];
    if (lane == 0) {
#pragma unroll
        for (int n = 0; n < NHEAD; ++n) sM[n][wave] = m[n];
    }
    __syncthreads();
    if (i == 0) {
        float o = 0.f;
#pragma unroll
        for (int n = 0; n < NHEAD; ++n) {
            float mm = fmaxf(fmaxf(sM[n][0], sM[n][1]), fmaxf(sM[n][2], sM[n][3]));
            o += mm * head_w[n];
        }
        out[b] = o;
    }
}

extern "C" void kernel_launch(void* const* d_in, const int* in_sizes, int n_in,
                              void* d_out, int out_size, void* d_ws, size_t ws_size,
                              hipStream_t stream) {
    const float* x      = (const float*)d_in[0];   // [B, T, H]
    const float* W      = (const float*)d_in[1];   // [NH, H]
    const float* bias   = (const float*)d_in[2];   // [NH]
    const float* decay  = (const float*)d_in[3];   // [NH]
    const float* head_w = (const float*)d_in[4];   // [1, NH]
    float* out = (float*)d_out;                    // [B]
    float* h   = (float*)d_ws;                     // [B, T, NH] scratch (4 MB)

    const int B = in_sizes[0] / (T_DIM * H_DIM);   // 64

    const int nblk = (B * T_DIM) / TT;             // 1024
    ema_gemv<<<nblk, TT, 0, stream>>>(x, W, bias, h);
    ema_scan<<<B, 256, 0, stream>>>(h, decay, head_w, out);
}

// Round 3
// 1314.692 us; speedup vs baseline: 1.2008x; 1.2008x over previous
//
#include <hip/hip_runtime.h>
#include <hip/hip_bf16.h>
#include <math.h>

#define T_DIM 4096
#define H_DIM 1024
#define NHEAD 4
#define TS_BLK 32   // timesteps per block in gemv kernel

// DPP-rotate add within a 16-lane row: x += rotate_row(x, N)
template <int CTRL>
__device__ __forceinline__ float dpp_ror_add(float x) {
    int r = __builtin_amdgcn_update_dpp(0, __float_as_int(x), CTRL, 0xF, 0xF, false);
    return x + __int_as_float(r);
}

// ---------------------------------------------------------------------------
// Kernel 1: h[b,t,n] = dot(x[b,t,:], W[n,:]) + bias[n]
// grid = (T/TS_BLK, B), block = 256 (4 waves). Each wave does one timestep at
// a time: 64 lanes * 4 float4 coalesced x loads; W cached in registers.
// Reduction: 4 DPP row-rotate levels (VALU) + 2 cross-row shfl levels with
// the 4 heads folded in -> only 3 DS ops per timestep (was 24).
// Result: lanes 0/16/32/48 hold heads 0/2/1/3 -> 4-dword coalesced store.
// ---------------------------------------------------------------------------
__global__ __launch_bounds__(256, 4) void ema_gemv(const float* __restrict__ x,
                                                   const float* __restrict__ W,
                                                   const float* __restrict__ bias,
                                                   float* __restrict__ h) {
    const int b    = blockIdx.y;
    const int t0   = blockIdx.x * TS_BLK;
    const int wave = threadIdx.x >> 6;
    const int lane = threadIdx.x & 63;

    // W fragment: lane holds W[n][c*256 + lane*4 .. +3] for n=0..3, c=0..3
    float4 wreg[NHEAD][4];
#pragma unroll
    for (int n = 0; n < NHEAD; ++n)
#pragma unroll
        for (int c = 0; c < 4; ++c)
            wreg[n][c] = *(const float4*)(W + n * H_DIM + c * 256 + lane * 4);

    // head owned by this lane after the fold (lanes 0/16/32/48 -> 0/2/1/3)
    const int head = ((lane & 16) ? 2 : 0) | ((lane & 32) ? 1 : 0);
    const float bh = bias[head];

    const int tpw = TS_BLK / 4;  // timesteps per wave = 8
    const float* xw = x + ((size_t)b * T_DIM + t0 + wave * tpw) * H_DIM;
    float* hw = h + ((size_t)b * T_DIM + t0 + wave * tpw) * NHEAD;

    float4 xv[2][4];
    // prefetch timestep 0
#pragma unroll
    for (int c = 0; c < 4; ++c)
        xv[0][c] = *(const float4*)(xw + c * 256 + lane * 4);

    for (int i = 0; i < tpw; ++i) {
        const int cur = i & 1;
        // prefetch next timestep
        if (i + 1 < tpw) {
            const float* xn = xw + (size_t)(i + 1) * H_DIM;
#pragma unroll
            for (int c = 0; c < 4; ++c)
                xv[cur ^ 1][c] = *(const float4*)(xn + c * 256 + lane * 4);
        }

        float acc[NHEAD] = {0.f, 0.f, 0.f, 0.f};
#pragma unroll
        for (int c = 0; c < 4; ++c) {
            const float4 v = xv[cur][c];
#pragma unroll
            for (int n = 0; n < NHEAD; ++n) {
                acc[n] += v.x * wreg[n][c].x + v.y * wreg[n][c].y
                        + v.z * wreg[n][c].z + v.w * wreg[n][c].w;
            }
        }

        // ---- reduce within 16-lane rows: 4 DPP rotate-add levels ----
#pragma unroll
        for (int n = 0; n < NHEAD; ++n) {
            acc[n] = dpp_ror_add<0x121>(acc[n]);   // ror:1
            acc[n] = dpp_ror_add<0x122>(acc[n]);   // ror:2
            acc[n] = dpp_ror_add<0x124>(acc[n]);   // ror:4
            acc[n] = dpp_ror_add<0x128>(acc[n]);   // ror:8
        }
        // ---- cross-row with head fold: 3 shfl_xor total ----
        const bool r16 = (lane & 16) != 0;
        const bool r32 = (lane & 32) != 0;
        float sendA = r16 ? acc[0] : acc[2];
        float sendB = r16 ? acc[1] : acc[3];
        float recvA = __shfl_xor(sendA, 16, 64);
        float recvB = __shfl_xor(sendB, 16, 64);
        float accA = (r16 ? acc[2] : acc[0]) + recvA;  // head (r16?2:0) over row-pair
        float accB = (r16 ? acc[3] : acc[1]) + recvB;  // head (r16?3:1) over row-pair
        float send = r32 ? accA : accB;
        float recv = __shfl_xor(send, 32, 64);
        float accF = (r32 ? accB : accA) + recv;       // full sum for `head`

        if ((lane & 15) == 0)
            hw[(size_t)i * NHEAD + head] = accF + bh;  // 4 lanes, one 16B segment
    }
}

// ---------------------------------------------------------------------------
// Kernel 2: per-batch parallel EMA scan + running max + head projection.
// grid = B, block = 256. Thread i owns segment [16i, 16i+16).
// Affine-map composition + Hillis-Steele over 256 segments, then replay
// with carry-in tracking max (max includes the 0 init, matching reference).
// ---------------------------------------------------------------------------
__global__ __launch_bounds__(256) void ema_scan(const float* __restrict__ h,
                                                const float* __restrict__ decay,
                                                const float* __restrict__ head_w,
                                                float* __restrict__ out) {
    const int b    = blockIdx.x;
    const int i    = threadIdx.x;   // 0..255
    const int lane = i & 63;
    const int wave = i >> 6;

    float dd[NHEAD], od[NHEAD];
#pragma unroll
    for (int n = 0; n < NHEAD; ++n) {
        dd[n] = 1.0f / (1.0f + expf(-decay[n]));
        od[n] = 1.0f - dd[n];
    }

    const float4* hrow = (const float4*)(h + (size_t)b * T_DIM * NHEAD);

    // local segment EMA from zero init
    float e[NHEAD] = {0.f, 0.f, 0.f, 0.f};
#pragma unroll
    for (int j = 0; j < 16; ++j) {
        float4 v = hrow[i * 16 + j];
        e[0] = dd[0] * e[0] + od[0] * v.x;
        e[1] = dd[1] * e[1] + od[1] * v.y;
        e[2] = dd[2] * e[2] + od[2] * v.z;
        e[3] = dd[3] * e[3] + od[3] * v.w;
    }
    float a[NHEAD];
#pragma unroll
    for (int n = 0; n < NHEAD; ++n) {
        float d2 = dd[n] * dd[n];
        float d4 = d2 * d2;
        float d8 = d4 * d4;
        a[n] = d8 * d8;   // d^16
    }
    float bb[NHEAD] = {e[0], e[1], e[2], e[3]};

    __shared__ float sA[NHEAD][256];
    __shared__ float sB[NHEAD][256];
#pragma unroll
    for (int n = 0; n < NHEAD; ++n) { sA[n][i] = a[n]; sB[n][i] = bb[n]; }
    __syncthreads();

    for (int off = 1; off < 256; off <<= 1) {
        float pa[NHEAD], pb[NHEAD];
        const bool has = (i >= off);
        if (has) {
#pragma unroll
            for (int n = 0; n < NHEAD; ++n) {
                pa[n] = sA[n][i - off];
                pb[n] = sB[n][i - off];
            }
        }
        __syncthreads();
        if (has) {
#pragma unroll
            for (int n = 0; n < NHEAD; ++n) {
                bb[n] = a[n] * pb[n] + bb[n];  // B_new = A_cur*B_prev + B_cur
                a[n]  = a[n] * pa[n];          // A_new = A_cur*A_prev
            }
        }
#pragma unroll
        for (int n = 0; n < NHEAD; ++n) { sA[n][i] = a[n]; sB[n][i] = bb[n]; }
        __syncthreads();
    }

    // carry-in for my segment = inclusive B of segment i-1 (0 for i==0)
    float e2[NHEAD], m[NHEAD];
#pragma unroll
    for (int n = 0; n < NHEAD; ++n) {
        e2[n] = (i > 0) ? sB[n][i - 1] : 0.0f;
        m[n]  = 0.0f;   // reference's emax starts at 0
    }
#pragma unroll
    for (int j = 0; j < 16; ++j) {
        float4 v = hrow[i * 16 + j];
        e2[0] = dd[0] * e2[0] + od[0] * v.x; m[0] = fmaxf(m[0], e2[0]);
        e2[1] = dd[1] * e2[1] + od[1] * v.y; m[1] = fmaxf(m[1], e2[1]);
        e2[2] = dd[2] * e2[2] + od[2] * v.z; m[2] = fmaxf(m[2], e2[2]);
        e2[3] = dd[3] * e2[3] + od[3] * v.w; m[3] = fmaxf(m[3], e2[3]);
    }

    // 64-lane max butterfly, then cross-wave via LDS
#pragma unroll
    for (int off = 32; off >= 1; off >>= 1)
#pragma unroll
        for (int n = 0; n < NHEAD; ++n)
            m[n] = fmaxf(m[n], __shfl_xor(m[n], off, 64));

    __shared__ float sM[NHEAD][4];
    if (lane == 0) {
#pragma unroll
        for (int n = 0; n < NHEAD; ++n) sM[n][wave] = m[n];
    }
    __syncthreads();
    if (i == 0) {
        float o = 0.f;
#pragma unroll
        for (int n = 0; n < NHEAD; ++n) {
            float mm = fmaxf(fmaxf(sM[n][0], sM[n][1]), fmaxf(sM[n][2], sM[n][3]));
            o += mm * head_w[n];
        }
        out[b] = o;
    }
}

extern "C" void kernel_launch(void* const* d_in, const int* in_sizes, int n_in,
                              void* d_out, int out_size, void* d_ws, size_t ws_size,
                              hipStream_t stream) {
    const float* x      = (const float*)d_in[0];   // [B, T, H]
    const float* W      = (const float*)d_in[1];   // [NH, H]
    const float* bias   = (const float*)d_in[2];   // [NH]
    const float* decay  = (const float*)d_in[3];   // [NH]
    const float* head_w = (const float*)d_in[4];   // [1, NH]
    float* out = (float*)d_out;                    // [B]
    float* h   = (float*)d_ws;                     // [B, T, NH] scratch (4 MB)

    const int B = in_sizes[0] / (T_DIM * H_DIM);   // 64

    dim3 g1(T_DIM / TS_BLK, B);
    ema_gemv<<<g1, 256, 0, stream>>>(x, W, bias, h);
    ema_scan<<<B, 256, 0, stream>>>(h, decay, head_w, out);
}